// Round 2
// baseline (105.723 us; speedup 1.0000x reference)
//
#include <hip/hip_runtime.h>

// Coords2Grid: libmolgrid-style density splat.
// out[t, x, y, z] = sum_n f(d(n, xyz)/r_n) * types[n, t]
//   f(u) = exp(-2 u^2)                 u < 1
//        = e^-2 (4u^2 - 12u + 9)       1 <= u < 1.5
//        = 0                           otherwise
#define GR   48
#define GR2  (GR * GR)
#define GR3  (GR * GR * GR)
#define NA   800
#define NT   28
#define RESF 0.5f
#define HALF_DIM 11.75f
#define INV_E2 0.13533528323661270f

__global__ __launch_bounds__(256) void c2g_kernel(
    const float* __restrict__ center,
    const float* __restrict__ coords,
    const float* __restrict__ types,
    const float* __restrict__ radii,
    float* __restrict__ out)
{
    __shared__ float s_ax[NA], s_ay[NA], s_az[NA], s_ir2[NA];
    __shared__ int   s_ai[NA];
    __shared__ int   s_cnt;

    const int tid = threadIdx.x;
    const int gid = blockIdx.x * 256 + tid;

    const float ox = center[0] - HALF_DIM;
    const float oy = center[1] - HALF_DIM;
    const float oz = center[2] - HALF_DIM;

    const int xi = gid / GR2;
    const int yi = (gid / GR) % GR;
    const int zi = gid % GR;
    const float gx = ox + xi * RESF;
    const float gy = oy + yi * RESF;
    const float gz = oz + zi * RESF;

    // Block bbox: 2304 = 9*256, so each block has a single x index,
    // spans y in [y0,y1], full z.
    const int gid0 = blockIdx.x * 256;
    const float bxv  = ox + (gid0 / GR2) * RESF;
    const int   y0   = (gid0 % GR2) / GR;
    const int   y1   = ((gid0 + 255) % GR2) / GR;
    const float bylo = oy + y0 * RESF, byhi = oy + y1 * RESF;
    const float bzlo = oz,             bzhi = oz + (GR - 1) * RESF;

    if (tid == 0) s_cnt = 0;
    __syncthreads();

    // Prefilter: atoms whose 1.5r sphere intersects the block bbox.
    for (int a = tid; a < NA; a += 256) {
        float ax = coords[3 * a + 0];
        float ay = coords[3 * a + 1];
        float az = coords[3 * a + 2];
        float r  = radii[a];
        float cut = 1.5f * r;
        // nearest point in bbox
        float ny = fminf(fmaxf(ay, bylo), byhi);
        float nz = fminf(fmaxf(az, bzlo), bzhi);
        float ddx = ax - bxv;
        float ddy = ay - ny;
        float ddz = az - nz;
        float d2 = ddx * ddx + ddy * ddy + ddz * ddz;
        if (d2 < cut * cut) {
            int p = atomicAdd(&s_cnt, 1);
            s_ax[p] = ax; s_ay[p] = ay; s_az[p] = az;
            s_ir2[p] = 1.0f / (r * r);
            s_ai[p] = a;
        }
    }
    __syncthreads();
    const int cnt = s_cnt;

    float acc[NT];
    #pragma unroll
    for (int t = 0; t < NT; ++t) acc[t] = 0.0f;

    for (int k = 0; k < cnt; ++k) {
        float dx = gx - s_ax[k];
        float dy = gy - s_ay[k];
        float dz = gz - s_az[k];
        float ir2 = s_ir2[k];
        float d2 = fmaf(dx, dx, fmaf(dy, dy, dz * dz));
        float dr2 = d2 * ir2;
        bool act = dr2 < 2.25f;
        if (!__any(act)) continue;

        // Branchless density (0 for inactive lanes).
        float g  = __expf(-2.0f * dr2);
        float dr = sqrtf(dr2);
        float q  = INV_E2 * fmaf(4.0f, dr2, fmaf(-12.0f, dr, 9.0f));
        float val = (dr2 < 1.0f) ? g : q;
        val = act ? val : 0.0f;

        // Wave-uniform atom index -> scalar loads of its 28 type weights.
        int a = __builtin_amdgcn_readfirstlane(s_ai[k]);
        const float4* tp = (const float4*)(types + a * NT);  // 112 B, 16B-aligned
        #pragma unroll
        for (int q4 = 0; q4 < NT / 4; ++q4) {
            float4 tv = tp[q4];
            acc[4 * q4 + 0] = fmaf(val, tv.x, acc[4 * q4 + 0]);
            acc[4 * q4 + 1] = fmaf(val, tv.y, acc[4 * q4 + 1]);
            acc[4 * q4 + 2] = fmaf(val, tv.z, acc[4 * q4 + 2]);
            acc[4 * q4 + 3] = fmaf(val, tv.w, acc[4 * q4 + 3]);
        }
    }

    #pragma unroll
    for (int t = 0; t < NT; ++t)
        out[t * GR3 + gid] = acc[t];
}

extern "C" void kernel_launch(void* const* d_in, const int* in_sizes, int n_in,
                              void* d_out, int out_size, void* d_ws, size_t ws_size,
                              hipStream_t stream) {
    const float* center = (const float*)d_in[0];
    const float* coords = (const float*)d_in[1];
    const float* types  = (const float*)d_in[2];
    const float* radii  = (const float*)d_in[3];
    float* out = (float*)d_out;

    dim3 grid(GR3 / 256);   // 432 blocks
    dim3 block(256);
    c2g_kernel<<<grid, block, 0, stream>>>(center, coords, types, radii, out);
}

// Round 3
// 102.745 us; speedup vs baseline: 1.0290x; 1.0290x over previous
//
#include <hip/hip_runtime.h>

// Coords2Grid: libmolgrid-style density splat.
// out[t, x, y, z] = sum_n f(d(n, xyz)/r_n) * types[n, t]
//   f(u) = exp(-2 u^2)                 u < 1
//        = e^-2 (4u^2 - 12u + 9)       1 <= u < 1.5
//        = 0                           otherwise
#define GR    48
#define GR2   (GR * GR)
#define GR3   (GR * GR * GR)
#define NA    800
#define NT    28
#define RESF  0.5f
#define HALF_DIM 11.75f
#define INV_E2 0.13533528323661270f
#define TILE  4
#define NTPD  (GR / TILE)          // 12 tiles per dim
#define NBLK  (NTPD * NTPD * NTPD) // 1728 blocks

__global__ __launch_bounds__(64) void c2g_kernel(
    const float* __restrict__ center,
    const float* __restrict__ coords,
    const float* __restrict__ types,
    const float* __restrict__ radii,
    float* __restrict__ out)
{
    __shared__ float s_ax[NA], s_ay[NA], s_az[NA], s_ir2[NA];
    __shared__ int   s_ai[NA];
    __shared__ int   s_cnt;

    const int tid = threadIdx.x;
    const int b   = blockIdx.x;
    const int tz  = b % NTPD;
    const int ty  = (b / NTPD) % NTPD;
    const int tx  = b / (NTPD * NTPD);

    const float ox = center[0] - HALF_DIM;
    const float oy = center[1] - HALF_DIM;
    const float oz = center[2] - HALF_DIM;

    // Tile point-bbox: TILE points spaced RESF, width (TILE-1)*RESF = 1.5
    const float bxlo = ox + tx * (TILE * RESF), bxhi = bxlo + (TILE - 1) * RESF;
    const float bylo = oy + ty * (TILE * RESF), byhi = bylo + (TILE - 1) * RESF;
    const float bzlo = oz + tz * (TILE * RESF), bzhi = bzlo + (TILE - 1) * RESF;

    if (tid == 0) s_cnt = 0;
    __syncthreads();

    // Prefilter: atoms whose 1.5r sphere reaches the tile's point bbox.
    for (int a = tid; a < NA; a += 64) {
        float ax = coords[3 * a + 0];
        float ay = coords[3 * a + 1];
        float az = coords[3 * a + 2];
        float r  = radii[a];
        float cut = 1.5f * r;
        float ddx = ax - fminf(fmaxf(ax, bxlo), bxhi);
        float ddy = ay - fminf(fmaxf(ay, bylo), byhi);
        float ddz = az - fminf(fmaxf(az, bzlo), bzhi);
        float d2 = fmaf(ddx, ddx, fmaf(ddy, ddy, ddz * ddz));
        if (d2 < cut * cut) {
            int p = atomicAdd(&s_cnt, 1);
            s_ax[p] = ax; s_ay[p] = ay; s_az[p] = az;
            s_ir2[p] = 1.0f / (r * r);
            s_ai[p] = a;
        }
    }
    __syncthreads();
    const int cnt = s_cnt;

    // Thread -> cell within tile (z fastest for store coalescing).
    const int lz = tid & 3;
    const int ly = (tid >> 2) & 3;
    const int lx = tid >> 4;
    const float gx = bxlo + lx * RESF;
    const float gy = bylo + ly * RESF;
    const float gz = bzlo + lz * RESF;

    float acc[NT];
    #pragma unroll
    for (int t = 0; t < NT; ++t) acc[t] = 0.0f;

    for (int k = 0; k < cnt; ++k) {
        float dx = gx - s_ax[k];
        float dy = gy - s_ay[k];
        float dz = gz - s_az[k];
        float ir2 = s_ir2[k];
        float d2 = fmaf(dx, dx, fmaf(dy, dy, dz * dz));
        float dr2 = d2 * ir2;
        bool act = dr2 < 2.25f;
        if (!__any(act)) continue;

        float g  = __expf(-2.0f * dr2);
        float dr = sqrtf(dr2);
        float q  = INV_E2 * fmaf(4.0f, dr2, fmaf(-12.0f, dr, 9.0f));
        float val = (dr2 < 1.0f) ? g : q;
        val = act ? val : 0.0f;

        // Wave-uniform atom index -> scalar (s_load) type row.
        int a = __builtin_amdgcn_readfirstlane(s_ai[k]);
        const float4* tp = (const float4*)(types + a * NT);  // 112 B row, 16B-aligned
        #pragma unroll
        for (int q4 = 0; q4 < NT / 4; ++q4) {
            float4 tv = tp[q4];
            acc[4 * q4 + 0] = fmaf(val, tv.x, acc[4 * q4 + 0]);
            acc[4 * q4 + 1] = fmaf(val, tv.y, acc[4 * q4 + 1]);
            acc[4 * q4 + 2] = fmaf(val, tv.z, acc[4 * q4 + 2]);
            acc[4 * q4 + 3] = fmaf(val, tv.w, acc[4 * q4 + 3]);
        }
    }

    const int gidx = ((tx * TILE + lx) * GR + (ty * TILE + ly)) * GR + tz * TILE + lz;
    #pragma unroll
    for (int t = 0; t < NT; ++t)
        out[t * GR3 + gidx] = acc[t];
}

extern "C" void kernel_launch(void* const* d_in, const int* in_sizes, int n_in,
                              void* d_out, int out_size, void* d_ws, size_t ws_size,
                              hipStream_t stream) {
    const float* center = (const float*)d_in[0];
    const float* coords = (const float*)d_in[1];
    const float* types  = (const float*)d_in[2];
    const float* radii  = (const float*)d_in[3];
    float* out = (float*)d_out;

    c2g_kernel<<<dim3(NBLK), dim3(64), 0, stream>>>(center, coords, types, radii, out);
}